// Round 1
// baseline (3555.165 us; speedup 1.0000x reference)
//
#include <hip/hip_runtime.h>
#include <hip/hip_bf16.h>
#include <stdint.h>

#define B_ 64
#define T_ 128
#define E_ 256
#define H_ 1024
#define G_ 4096   // 4*H
#define V_ 32000

typedef __attribute__((ext_vector_type(8))) short short8;
typedef __attribute__((ext_vector_type(8))) unsigned short ushort8;
typedef __attribute__((ext_vector_type(4))) float floatx4;

static __device__ __forceinline__ unsigned short f2bf(float f){
  union { float f; unsigned u; } v; v.f = f;
  unsigned r = v.u + 0x7FFFu + ((v.u >> 16) & 1u);  // RNE
  return (unsigned short)(r >> 16);
}
static __device__ __forceinline__ float bf2f(unsigned short s){
  union { unsigned u; float f; } v; v.u = ((unsigned)s) << 16;
  return v.f;
}
static __device__ __forceinline__ float sigmoidf_(float x){
  return 1.0f / (1.0f + __expf(-x));
}

// ---------------- transpose + bf16-convert the fused LSTM kernel ----------------
// kern: [1280][4096] fp32 row-major.  wx_t: [4096][256] bf16, wh_t: [4096][1024] bf16
__global__ __launch_bounds__(256) void k_transpose(const float* __restrict__ kern,
    unsigned short* __restrict__ wx_t, unsigned short* __restrict__ wh_t){
  __shared__ float tile[32][36];
  const int k0 = blockIdx.x * 32, g0 = blockIdx.y * 32;
  const int r  = threadIdx.x >> 3;
  const int c4 = (threadIdx.x & 7) << 2;
  const float4 v = *reinterpret_cast<const float4*>(kern + (size_t)(k0 + r) * G_ + g0 + c4);
  tile[r][c4 + 0] = v.x; tile[r][c4 + 1] = v.y;
  tile[r][c4 + 2] = v.z; tile[r][c4 + 3] = v.w;
  __syncthreads();
  const unsigned short o0 = f2bf(tile[c4 + 0][r]);
  const unsigned short o1 = f2bf(tile[c4 + 1][r]);
  const unsigned short o2 = f2bf(tile[c4 + 2][r]);
  const unsigned short o3 = f2bf(tile[c4 + 3][r]);
  const ushort4 pk = make_ushort4(o0, o1, o2, o3);
  if (k0 < E_)
    *reinterpret_cast<ushort4*>(wx_t + (size_t)(g0 + r) * E_ + (k0 + c4)) = pk;
  else
    *reinterpret_cast<ushort4*>(wh_t + (size_t)(g0 + r) * H_ + (k0 - E_ + c4)) = pk;
}

// ---------------- xgates[r=t*64+b][g] = (x_t @ Wx)[b][g] + bias[g], stored bf16 ----------------
// grid (128 Mtiles, 64 Ntiles), block 256 (4 waves). Wave = one 16-row M strip, 4 N-tiles of 16.
__global__ __launch_bounds__(256) void k_xgates(const float* __restrict__ x,
    const unsigned short* __restrict__ wx_t, const float* __restrict__ bias,
    unsigned short* __restrict__ xg){
  const int w = threadIdx.x >> 6, l = threadIdx.x & 63;
  const int quad = l >> 4, n = l & 15;
  const int Mbase = blockIdx.x * 64 + w * 16;
  const int Nbase = blockIdx.y * 64;
  const int r = Mbase + n;              // row = t*64 + b
  const int b = r & 63, t = r >> 6;
  const float* arow = x + ((size_t)b * T_ + t) * E_;
  floatx4 acc[4] = {{0,0,0,0},{0,0,0,0},{0,0,0,0},{0,0,0,0}};
  #pragma unroll
  for (int kt = 0; kt < 8; ++kt){
    const int k0 = kt * 32 + quad * 8;
    const float4 f0 = *reinterpret_cast<const float4*>(arow + k0);
    const float4 f1 = *reinterpret_cast<const float4*>(arow + k0 + 4);
    short8 af;
    af[0] = (short)f2bf(f0.x); af[1] = (short)f2bf(f0.y);
    af[2] = (short)f2bf(f0.z); af[3] = (short)f2bf(f0.w);
    af[4] = (short)f2bf(f1.x); af[5] = (short)f2bf(f1.y);
    af[6] = (short)f2bf(f1.z); af[7] = (short)f2bf(f1.w);
    const unsigned short* bp = wx_t + (size_t)(Nbase + n) * E_ + k0;
    #pragma unroll
    for (int nt = 0; nt < 4; ++nt){
      const short8 bf = *reinterpret_cast<const short8*>(bp + (size_t)nt * 16 * E_);
      acc[nt] = __builtin_amdgcn_mfma_f32_16x16x32_bf16(af, bf, acc[nt], 0, 0, 0);
    }
  }
  const int rbase = Mbase + quad * 4;
  #pragma unroll
  for (int nt = 0; nt < 4; ++nt){
    const int g = Nbase + nt * 16 + n;
    const float bi = bias[g];
    #pragma unroll
    for (int reg = 0; reg < 4; ++reg){
      xg[(size_t)(rbase + reg) * G_ + g] = f2bf(acc[nt][reg] + bi);
    }
  }
}

// ---------------- persistent LSTM: 256 WGs, one per CU, grid barrier per step ----------------
#define AP_ 136    // Ash pitch (ushorts): 128 + 8 pad -> 2-way-free LDS banks
#define BP_ 1032   // Bsh pitch (ushorts): 1024 + 8 pad
__global__ __launch_bounds__(256) void k_lstm(const unsigned short* __restrict__ wh_t,
    const unsigned short* __restrict__ xg,
    unsigned short* __restrict__ hb0, unsigned short* __restrict__ hb1,
    float* __restrict__ hT, unsigned int* __restrict__ bar){
  __shared__ unsigned short Bsh[16 * BP_];  // resident Wh slice: 16 gate-cols x 1024 k
  __shared__ unsigned short Ash[64 * AP_];  // h chunk: 64 b x 128 k
  const int tid = threadIdx.x;
  const int wg = blockIdx.x;                // 0..255, owns h-cols [wg*4, wg*4+4)
  const int hbase = wg * 4;
  const int w = tid >> 6, l = tid & 63, quad = l >> 4, n = l & 15;

  { // load Wh slice once: col c -> gate (c>>2), h-col hbase+(c&3)
    const int c = tid >> 4, sg = tid & 15;
    const int g = (c >> 2) * H_ + hbase + (c & 3);
    const unsigned short* src = wh_t + (size_t)g * H_;
    unsigned short* dst = &Bsh[c * BP_];
    #pragma unroll
    for (int i = 0; i < 4; ++i){
      const int off = sg * 64 + i * 16;
      *reinterpret_cast<ushort8*>(dst + off)     = *reinterpret_cast<const ushort8*>(src + off);
      *reinterpret_cast<ushort8*>(dst + off + 8) = *reinterpret_cast<const ushort8*>(src + off + 8);
    }
  }
  float creg[4] = {0.f, 0.f, 0.f, 0.f};     // c state lives in registers (lanes n<4)
  const int g_lane = (n >> 2) * H_ + hbase + (n & 3);
  const int rowb = w * 16 + quad * 4;
  const int aoff = (w * 16 + n) * AP_;
  const int boff = n * BP_;
  const bool low8  = (n & 8) == 0;          // lanes holding (i,j) pairs
  const bool first = (n & 4) == 0;          // first gate of the pair
  const int rowA = tid >> 2, ko = (tid & 3) * 32;
  __syncthreads();

  for (int t = 0; t < T_; ++t){
    const unsigned short* __restrict__ hin = (t & 1) ? hb1 : hb0;
    unsigned short* __restrict__ hout      = (t & 1) ? hb0 : hb1;
    const unsigned short* xgt = xg + (size_t)t * 64 * G_;
    // init accumulator from precomputed x-gates (C/D layout: row=quad*4+reg, col=n)
    floatx4 acc;
    acc[0] = bf2f(xgt[(size_t)(rowb + 0) * G_ + g_lane]);
    acc[1] = bf2f(xgt[(size_t)(rowb + 1) * G_ + g_lane]);
    acc[2] = bf2f(xgt[(size_t)(rowb + 2) * G_ + g_lane]);
    acc[3] = bf2f(xgt[(size_t)(rowb + 3) * G_ + g_lane]);

    for (int kc = 0; kc < 8; ++kc){
      __syncthreads();
      { // stage h chunk [64][128] bf16 into LDS
        const unsigned short* s = hin + (size_t)rowA * H_ + kc * 128 + ko;
        unsigned short* d = &Ash[rowA * AP_ + ko];
        *reinterpret_cast<ushort8*>(d)      = *reinterpret_cast<const ushort8*>(s);
        *reinterpret_cast<ushort8*>(d + 8)  = *reinterpret_cast<const ushort8*>(s + 8);
        *reinterpret_cast<ushort8*>(d + 16) = *reinterpret_cast<const ushort8*>(s + 16);
        *reinterpret_cast<ushort8*>(d + 24) = *reinterpret_cast<const ushort8*>(s + 24);
      }
      __syncthreads();
      #pragma unroll
      for (int kt = 0; kt < 4; ++kt){
        const int kk = kt * 32 + quad * 8;
        const short8 af = *reinterpret_cast<const short8*>(&Ash[aoff + kk]);
        const short8 bf = *reinterpret_cast<const short8*>(&Bsh[boff + kc * 128 + kk]);
        acc = __builtin_amdgcn_mfma_f32_16x16x32_bf16(af, bf, acc, 0, 0, 0);
      }
    }
    // pointwise: lane col n -> gate n>>2, h-offset n&3.  Pair up via shuffles.
    float r1o[4], q1[4], q2[4];
    #pragma unroll
    for (int reg = 0; reg < 4; ++reg){
      const float a_ = acc[reg];
      const float p_ = __shfl_xor(a_, 4);   // swap i<->j and f<->o
      const float x1 = first ? a_ : p_;     // i (low) / f (high)
      const float x2 = first ? p_ : a_;     // j (low) / o (high)
      const float s1 = sigmoidf_(low8 ? x1 : (x1 + 1.0f));   // sig(i) or sig(f+FORGET_BIAS)
      const float r1 = low8 ? s1 * tanhf(x2) : s1;           // sig(i)*tanh(j) or sig(f+1)
      const float r2 = low8 ? 0.0f : sigmoidf_(x2);          // sig(o)
      r1o[reg] = r1;
      q1[reg] = __shfl_xor(r1, 8);          // low lanes receive sig(f+1)
      q2[reg] = __shfl_xor(r2, 8);          // low lanes receive sig(o)
    }
    if (n < 4){
      #pragma unroll
      for (int reg = 0; reg < 4; ++reg){
        const float cn = creg[reg] * q1[reg] + r1o[reg];
        creg[reg] = cn;
        const float hv = tanhf(cn) * q2[reg];
        hout[(size_t)(rowb + reg) * H_ + hbase + n] = f2bf(hv);
        if (t == T_ - 1) hT[(size_t)(hbase + n) * B_ + rowb + reg] = hv;
      }
    }
    // grid barrier (two-level, monotonic counters; skipped after last step)
    if (t < T_ - 1){
      __syncthreads();                      // drains all lanes' h stores (vmcnt=0)
      if (tid == 0){
        __threadfence();                    // agent release: writeback
        const unsigned tgt = (unsigned)(t + 1);
        unsigned prev = __hip_atomic_fetch_add(&bar[wg >> 5], 1u, __ATOMIC_RELEASE, __HIP_MEMORY_SCOPE_AGENT);
        if (prev == tgt * 32u - 1u){
          unsigned p2 = __hip_atomic_fetch_add(&bar[8], 1u, __ATOMIC_ACQ_REL, __HIP_MEMORY_SCOPE_AGENT);
          if (p2 == tgt * 8u - 1u){
            __hip_atomic_store(&bar[9], tgt, __ATOMIC_RELEASE, __HIP_MEMORY_SCOPE_AGENT);
          }
        }
        while (__hip_atomic_load(&bar[9], __ATOMIC_RELAXED, __HIP_MEMORY_SCOPE_AGENT) < tgt){
          __builtin_amdgcn_s_sleep(1);
        }
        __threadfence();                    // agent acquire: invalidate stale h lines
      }
      __syncthreads();
    }
  }
}

// ---------------- final projection: out = h127 @ w_out + b_out (fp32 vector, K-split 4) ----------------
// grid (125 v-blocks of 256, 4 k-parts), block 256. Thread: 4 v-cols x 16 b-rows.
__global__ __launch_bounds__(256) void k_proj(const float* __restrict__ w_out,
    const float* __restrict__ hT, float* __restrict__ part){
  __shared__ float wsh[32 * 260];
  __shared__ float hsh[32 * 68];
  const int tid = threadIdx.x;
  const int vb = blockIdx.x, ky = blockIdx.y;
  const int vq = tid & 63, bg = tid >> 6;   // bg == wave id -> hsh reads are broadcast
  const int vbase = vb * 256;
  floatx4 acc[16];
  #pragma unroll
  for (int i = 0; i < 16; ++i) acc[i] = (floatx4){0.f, 0.f, 0.f, 0.f};
  for (int c = 0; c < 8; ++c){
    const int k0 = ky * 256 + c * 32;
    __syncthreads();
    #pragma unroll
    for (int i = 0; i < 8; ++i){            // stage w: 32 k x 256 v
      const int flat = tid + i * 256;
      const int row = flat >> 6, c4 = (flat & 63) << 2;
      *reinterpret_cast<float4*>(&wsh[row * 260 + c4]) =
        *reinterpret_cast<const float4*>(w_out + (size_t)(k0 + row) * V_ + vbase + c4);
    }
    #pragma unroll
    for (int i = 0; i < 2; ++i){            // stage hT: 32 k x 64 b
      const int flat = tid + i * 256;
      const int row = flat >> 4, c4 = (flat & 15) << 2;
      *reinterpret_cast<float4*>(&hsh[row * 68 + c4]) =
        *reinterpret_cast<const float4*>(hT + (k0 + row) * B_ + c4);
    }
    __syncthreads();
    #pragma unroll 4
    for (int k = 0; k < 32; ++k){
      const floatx4 wv = *reinterpret_cast<const floatx4*>(&wsh[k * 260 + vq * 4]);
      #pragma unroll
      for (int j = 0; j < 4; ++j){
        const floatx4 hv = *reinterpret_cast<const floatx4*>(&hsh[k * 68 + bg * 16 + j * 4]);
        acc[j * 4 + 0] += hv[0] * wv;
        acc[j * 4 + 1] += hv[1] * wv;
        acc[j * 4 + 2] += hv[2] * wv;
        acc[j * 4 + 3] += hv[3] * wv;
      }
    }
  }
  float* pbase = part + ((size_t)ky * B_ + bg * 16) * V_ + vbase + vq * 4;
  #pragma unroll
  for (int i = 0; i < 16; ++i){
    *reinterpret_cast<floatx4*>(pbase + (size_t)i * V_) = acc[i];
  }
}

__global__ __launch_bounds__(256) void k_reduce(const float* __restrict__ part,
    const float* __restrict__ b_out, float* __restrict__ out){
  const int f4 = blockIdx.x * 256 + threadIdx.x;          // 0..511999 float4s
  const floatx4* P = reinterpret_cast<const floatx4*>(part);
  floatx4 s = P[f4] + P[f4 + 512000] + P[f4 + 1024000] + P[f4 + 1536000];
  const int v = (f4 * 4) % V_;
  s += *reinterpret_cast<const floatx4*>(b_out + v);
  reinterpret_cast<floatx4*>(out)[f4] = s;
}

extern "C" void kernel_launch(void* const* d_in, const int* in_sizes, int n_in,
                              void* d_out, int out_size, void* d_ws, size_t ws_size,
                              hipStream_t stream){
  (void)in_sizes; (void)n_in; (void)out_size; (void)ws_size;
  const float* x     = (const float*)d_in[0];
  const float* kern  = (const float*)d_in[1];
  const float* bias  = (const float*)d_in[2];
  const float* w_out = (const float*)d_in[3];
  const float* b_out = (const float*)d_in[4];
  float* out = (float*)d_out;
  char* ws = (char*)d_ws;

  const size_t BAR_OFF = 0;                        // 256 B barrier state
  const size_t H0_OFF  = 256;                      // h buffer 0, bf16 [64][1024]
  const size_t H1_OFF  = H0_OFF + 131072;          // h buffer 1
  const size_t HT_OFF  = H1_OFF + 131072;          // h127 transposed fp32 [1024][64]
  const size_t WX_OFF  = HT_OFF + 262144;          // Wx^T bf16 [4096][256]
  const size_t WH_OFF  = WX_OFF + 2097152;         // Wh^T bf16 [4096][1024]
  const size_t XG_OFF  = WH_OFF + 8388608;         // xgates bf16 [128*64][4096] (67 MB)
  const size_t PART_OFF = XG_OFF;                  // proj partials overlap xg (used after LSTM)

  unsigned int*   bar  = (unsigned int*)(ws + BAR_OFF);
  unsigned short* h0   = (unsigned short*)(ws + H0_OFF);
  unsigned short* h1   = (unsigned short*)(ws + H1_OFF);
  float*          hT   = (float*)(ws + HT_OFF);
  unsigned short* wx_t = (unsigned short*)(ws + WX_OFF);
  unsigned short* wh_t = (unsigned short*)(ws + WH_OFF);
  unsigned short* xg   = (unsigned short*)(ws + XG_OFF);
  float*          part = (float*)(ws + PART_OFF);

  hipMemsetAsync(ws, 0, HT_OFF, stream);  // zero barrier + h0 + h1 every launch
  k_transpose<<<dim3(40, 128), 256, 0, stream>>>(kern, wx_t, wh_t);
  k_xgates<<<dim3(128, 64), 256, 0, stream>>>(x, wx_t, bias, xg);
  k_lstm<<<dim3(256), 256, 0, stream>>>(wh_t, xg, h0, h1, hT, bar);
  k_proj<<<dim3(125, 4), 256, 0, stream>>>(w_out, hT, part);
  k_reduce<<<dim3(2000), 256, 0, stream>>>(part, b_out, out);
}

// Round 2
// 1891.692 us; speedup vs baseline: 1.8794x; 1.8794x over previous
//
#include <hip/hip_runtime.h>
#include <hip/hip_bf16.h>
#include <stdint.h>

#define B_ 64
#define T_ 128
#define E_ 256
#define H_ 1024
#define G_ 4096   // 4*H
#define V_ 32000
#define HS_ 65536 // elements per h buffer (64 rows x 1024 cols, bf16)

typedef __attribute__((ext_vector_type(8))) short short8;
typedef __attribute__((ext_vector_type(4))) float floatx4;

static __device__ __forceinline__ unsigned short f2bf(float f){
  union { float f; unsigned u; } v; v.f = f;
  unsigned r = v.u + 0x7FFFu + ((v.u >> 16) & 1u);  // RNE
  return (unsigned short)(r >> 16);
}
static __device__ __forceinline__ float bf2f(unsigned short s){
  union { unsigned u; float f; } v; v.u = ((unsigned)s) << 16;
  return v.f;
}
static __device__ __forceinline__ float sigmoidf_(float x){
  return 1.0f / (1.0f + __expf(-x));
}

// ---------------- transpose + bf16-convert the fused LSTM kernel ----------------
// kern: [1280][4096] fp32 row-major.  wx_t: [4096][256] bf16, wh_t: [4096][1024] bf16
__global__ __launch_bounds__(256) void k_transpose(const float* __restrict__ kern,
    unsigned short* __restrict__ wx_t, unsigned short* __restrict__ wh_t){
  __shared__ float tile[32][36];
  const int k0 = blockIdx.x * 32, g0 = blockIdx.y * 32;
  const int r  = threadIdx.x >> 3;
  const int c4 = (threadIdx.x & 7) << 2;
  const float4 v = *reinterpret_cast<const float4*>(kern + (size_t)(k0 + r) * G_ + g0 + c4);
  tile[r][c4 + 0] = v.x; tile[r][c4 + 1] = v.y;
  tile[r][c4 + 2] = v.z; tile[r][c4 + 3] = v.w;
  __syncthreads();
  const unsigned short o0 = f2bf(tile[c4 + 0][r]);
  const unsigned short o1 = f2bf(tile[c4 + 1][r]);
  const unsigned short o2 = f2bf(tile[c4 + 2][r]);
  const unsigned short o3 = f2bf(tile[c4 + 3][r]);
  const ushort4 pk = make_ushort4(o0, o1, o2, o3);
  if (k0 < E_)
    *reinterpret_cast<ushort4*>(wx_t + (size_t)(g0 + r) * E_ + (k0 + c4)) = pk;
  else
    *reinterpret_cast<ushort4*>(wh_t + (size_t)(g0 + r) * H_ + (k0 - E_ + c4)) = pk;
}

// ---------------- xgates, stored PERMUTED for the LSTM: ----------------
// xgp element ((t*256 + wg)*256 + lstm_tid)*4 + reg  (bf16)
// where lstm_tid = w*64 + quad*16 + n', row b = w*16 + quad*4 + reg,
//       col g = gate*1024 + wg*4 + c, n' = gate*4 + c.
__global__ __launch_bounds__(256) void k_xgates(const float* __restrict__ x,
    const unsigned short* __restrict__ wx_t, const float* __restrict__ bias,
    unsigned short* __restrict__ xgp){
  const int w = threadIdx.x >> 6, l = threadIdx.x & 63;
  const int quad = l >> 4, n = l & 15;
  const int Mbase = blockIdx.x * 64 + w * 16;
  const int Nbase = blockIdx.y * 64;
  const int r = Mbase + n;              // row = t*64 + b
  const int b = r & 63, t = r >> 6;
  const float* arow = x + ((size_t)b * T_ + t) * E_;
  floatx4 acc[4] = {{0,0,0,0},{0,0,0,0},{0,0,0,0},{0,0,0,0}};
  #pragma unroll
  for (int kt = 0; kt < 8; ++kt){
    const int k0 = kt * 32 + quad * 8;
    const float4 f0 = *reinterpret_cast<const float4*>(arow + k0);
    const float4 f1 = *reinterpret_cast<const float4*>(arow + k0 + 4);
    short8 af;
    af[0] = (short)f2bf(f0.x); af[1] = (short)f2bf(f0.y);
    af[2] = (short)f2bf(f0.z); af[3] = (short)f2bf(f0.w);
    af[4] = (short)f2bf(f1.x); af[5] = (short)f2bf(f1.y);
    af[6] = (short)f2bf(f1.z); af[7] = (short)f2bf(f1.w);
    const unsigned short* bp = wx_t + (size_t)(Nbase + n) * E_ + k0;
    #pragma unroll
    for (int nt = 0; nt < 4; ++nt){
      const short8 bf = *reinterpret_cast<const short8*>(bp + (size_t)nt * 16 * E_);
      acc[nt] = __builtin_amdgcn_mfma_f32_16x16x32_bf16(af, bf, acc[nt], 0, 0, 0);
    }
  }
  // epilogue: permuted 8B stores.  t_out = blockIdx.x for all our output rows.
  const int t_out = blockIdx.x;
  const int np = (blockIdx.y >> 4) * 4 + (n & 3);     // gate*4 + c
  #pragma unroll
  for (int nt = 0; nt < 4; ++nt){
    const int g = Nbase + nt * 16 + n;
    const float bi = bias[g];
    const int wgd = ((blockIdx.y & 15) << 4) + nt * 4 + (n >> 2);
    ushort4 pk;
    pk.x = f2bf(acc[nt][0] + bi);
    pk.y = f2bf(acc[nt][1] + bi);
    pk.z = f2bf(acc[nt][2] + bi);
    pk.w = f2bf(acc[nt][3] + bi);
    *reinterpret_cast<ushort4*>(xgp +
        (((size_t)t_out * 256 + wgd) * 256 + w * 64 + quad * 16 + np) * 4) = pk;
  }
}

// ---------------- persistent LSTM: 256 WGs, 0 LDS, register-resident Wh slice ----------------
// hb: 129 h buffers (address-renamed per step -> no stale caches, no fences).
__global__ __launch_bounds__(256, 1) void k_lstm(const unsigned short* __restrict__ wh_t,
    const unsigned short* __restrict__ xgp, unsigned short* __restrict__ hb,
    float* __restrict__ hT, unsigned int* __restrict__ bar){
  const int tid = threadIdx.x;
  const int wg = blockIdx.x;                // owns h-cols [wg*4, wg*4+4)
  const int hbase = wg * 4;
  const int w = tid >> 6, l = tid & 63, quad = l >> 4, n = l & 15;
  const int g_lane = (n >> 2) * H_ + hbase + (n & 3);
  const int rowb = w * 16 + quad * 4;
  const bool low8  = (n & 8) == 0;          // lanes holding (i,j) pairs
  const bool first = (n & 4) == 0;          // first gate of the pair

  // Preload B-fragments (this WG's Wh slice) into registers: 32 x 16B per lane.
  short8 bfr[32];
  {
    const unsigned short* bp = wh_t + (size_t)g_lane * H_ + quad * 8;
    #pragma unroll
    for (int kt = 0; kt < 32; ++kt)
      bfr[kt] = *reinterpret_cast<const short8*>(bp + kt * 32);
  }
  float creg[4] = {0.f, 0.f, 0.f, 0.f};

  for (int t = 0; t < T_; ++t){
    // xg init values (contiguous 8B per lane, permuted layout)
    const ushort4 xgv = *reinterpret_cast<const ushort4*>(
        xgp + (((size_t)t * 256 + wg) * 256 + tid) * 4);
    // A-fragments: one burst of 32 x 16B loads of h_t (plain cached loads;
    // addresses are fresh every step so no cache can be stale)
    const unsigned short* asrc = hb + (size_t)t * HS_ + (size_t)(w * 16 + n) * H_ + quad * 8;
    short8 afr[32];
    #pragma unroll
    for (int kt = 0; kt < 32; ++kt)
      afr[kt] = *reinterpret_cast<const short8*>(asrc + kt * 32);

    floatx4 acc0 = {0.f,0.f,0.f,0.f}, acc1 = {0.f,0.f,0.f,0.f};
    #pragma unroll
    for (int kt = 0; kt < 32; kt += 2){
      acc0 = __builtin_amdgcn_mfma_f32_16x16x32_bf16(afr[kt],     bfr[kt],     acc0, 0, 0, 0);
      acc1 = __builtin_amdgcn_mfma_f32_16x16x32_bf16(afr[kt + 1], bfr[kt + 1], acc1, 0, 0, 0);
    }
    floatx4 acc = acc0 + acc1;
    acc[0] += bf2f(xgv.x); acc[1] += bf2f(xgv.y);
    acc[2] += bf2f(xgv.z); acc[3] += bf2f(xgv.w);

    // pointwise: lane col n -> gate n>>2, h-offset n&3.  Pair up via shuffles.
    float r1o[4], q1[4], q2[4];
    #pragma unroll
    for (int reg = 0; reg < 4; ++reg){
      const float a_ = acc[reg];
      const float p_ = __shfl_xor(a_, 4);   // swap i<->j and f<->o
      const float x1 = first ? a_ : p_;     // i (low) / f (high)
      const float x2 = first ? p_ : a_;     // j (low) / o (high)
      const float s1 = sigmoidf_(low8 ? x1 : (x1 + 1.0f));   // sig(i) or sig(f+1)
      const float r1 = low8 ? s1 * tanhf(x2) : s1;           // sig(i)*tanh(j) or sig(f+1)
      const float r2 = low8 ? 0.0f : sigmoidf_(x2);          // sig(o)
      r1o[reg] = r1;
      q1[reg] = __shfl_xor(r1, 8);          // low lanes receive sig(f+1)
      q2[reg] = __shfl_xor(r2, 8);          // low lanes receive sig(o)
    }
    if (n < 4){
      unsigned short* hout = hb + (size_t)(t + 1) * HS_;
      #pragma unroll
      for (int reg = 0; reg < 4; ++reg){
        const float cn = creg[reg] * q1[reg] + r1o[reg];
        creg[reg] = cn;
        const float hv = tanhf(cn) * q2[reg];
        // agent-scope relaxed store -> write-through (sc0 sc1), visible at L3
        __hip_atomic_store(&hout[(size_t)(rowb + reg) * H_ + hbase + n], f2bf(hv),
                           __ATOMIC_RELAXED, __HIP_MEMORY_SCOPE_AGENT);
        if (t == T_ - 1) hT[(size_t)(hbase + n) * B_ + rowb + reg] = hv;
      }
    }
    // grid barrier: pure relaxed atomics, no cache-sweeping fences.
    if (t < T_ - 1){
      __syncthreads();                      // emits s_waitcnt vmcnt(0) before s_barrier
      if (tid == 0){
        const unsigned tgt = (unsigned)(t + 1);
        __asm__ volatile("" ::: "memory");
        unsigned prev = __hip_atomic_fetch_add(&bar[wg >> 5], 1u,
                          __ATOMIC_RELAXED, __HIP_MEMORY_SCOPE_AGENT);
        if (prev == tgt * 32u - 1u){
          unsigned p2 = __hip_atomic_fetch_add(&bar[8], 1u,
                          __ATOMIC_RELAXED, __HIP_MEMORY_SCOPE_AGENT);
          if (p2 == tgt * 8u - 1u){
            __hip_atomic_store(&bar[9], tgt, __ATOMIC_RELAXED, __HIP_MEMORY_SCOPE_AGENT);
          }
        }
        while (__hip_atomic_load(&bar[9], __ATOMIC_RELAXED, __HIP_MEMORY_SCOPE_AGENT) < tgt){
          __builtin_amdgcn_s_sleep(1);
        }
        __asm__ volatile("" ::: "memory");
      }
      __syncthreads();
    }
  }
}

// ---------------- final projection: out = h127 @ w_out + b_out (fp32 vector, K-split 4) ----------------
__global__ __launch_bounds__(256) void k_proj(const float* __restrict__ w_out,
    const float* __restrict__ hT, float* __restrict__ part){
  __shared__ float wsh[32 * 260];
  __shared__ float hsh[32 * 68];
  const int tid = threadIdx.x;
  const int vb = blockIdx.x, ky = blockIdx.y;
  const int vq = tid & 63, bg = tid >> 6;
  const int vbase = vb * 256;
  floatx4 acc[16];
  #pragma unroll
  for (int i = 0; i < 16; ++i) acc[i] = (floatx4){0.f, 0.f, 0.f, 0.f};
  for (int c = 0; c < 8; ++c){
    const int k0 = ky * 256 + c * 32;
    __syncthreads();
    #pragma unroll
    for (int i = 0; i < 8; ++i){
      const int flat = tid + i * 256;
      const int row = flat >> 6, c4 = (flat & 63) << 2;
      *reinterpret_cast<float4*>(&wsh[row * 260 + c4]) =
        *reinterpret_cast<const float4*>(w_out + (size_t)(k0 + row) * V_ + vbase + c4);
    }
    #pragma unroll
    for (int i = 0; i < 2; ++i){
      const int flat = tid + i * 256;
      const int row = flat >> 4, c4 = (flat & 15) << 2;
      *reinterpret_cast<float4*>(&hsh[row * 68 + c4]) =
        *reinterpret_cast<const float4*>(hT + (k0 + row) * B_ + c4);
    }
    __syncthreads();
    #pragma unroll 4
    for (int k = 0; k < 32; ++k){
      const floatx4 wv = *reinterpret_cast<const floatx4*>(&wsh[k * 260 + vq * 4]);
      #pragma unroll
      for (int j = 0; j < 4; ++j){
        const floatx4 hv = *reinterpret_cast<const floatx4*>(&hsh[k * 68 + bg * 16 + j * 4]);
        acc[j * 4 + 0] += hv[0] * wv;
        acc[j * 4 + 1] += hv[1] * wv;
        acc[j * 4 + 2] += hv[2] * wv;
        acc[j * 4 + 3] += hv[3] * wv;
      }
    }
  }
  float* pbase = part + ((size_t)ky * B_ + bg * 16) * V_ + vbase + vq * 4;
  #pragma unroll
  for (int i = 0; i < 16; ++i){
    *reinterpret_cast<floatx4*>(pbase + (size_t)i * V_) = acc[i];
  }
}

__global__ __launch_bounds__(256) void k_reduce(const float* __restrict__ part,
    const float* __restrict__ b_out, float* __restrict__ out){
  const int f4 = blockIdx.x * 256 + threadIdx.x;          // 0..511999 float4s
  const floatx4* P = reinterpret_cast<const floatx4*>(part);
  floatx4 s = P[f4] + P[f4 + 512000] + P[f4 + 1024000] + P[f4 + 1536000];
  const int v = (f4 * 4) % V_;
  s += *reinterpret_cast<const floatx4*>(b_out + v);
  reinterpret_cast<floatx4*>(out)[f4] = s;
}

extern "C" void kernel_launch(void* const* d_in, const int* in_sizes, int n_in,
                              void* d_out, int out_size, void* d_ws, size_t ws_size,
                              hipStream_t stream){
  (void)in_sizes; (void)n_in; (void)out_size; (void)ws_size;
  const float* x     = (const float*)d_in[0];
  const float* kern  = (const float*)d_in[1];
  const float* bias  = (const float*)d_in[2];
  const float* w_out = (const float*)d_in[3];
  const float* b_out = (const float*)d_in[4];
  float* out = (float*)d_out;
  char* ws = (char*)d_ws;

  const size_t BAR_OFF = 0;                              // 4 KB barrier state
  const size_t HB_OFF  = 4096;                           // 129 h buffers, bf16 [64][1024] each
  const size_t HT_OFF  = HB_OFF + (size_t)129 * 131072;  // h127 transposed fp32 [1024][64]
  const size_t WX_OFF  = HT_OFF + 262144;                // Wx^T bf16 [4096][256]
  const size_t WH_OFF  = WX_OFF + 2097152;               // Wh^T bf16 [4096][1024]
  const size_t XG_OFF  = WH_OFF + 8388608;               // xgates bf16 permuted (67 MB)
  const size_t PART_OFF = XG_OFF;                        // proj partials overlap xg

  unsigned int*   bar  = (unsigned int*)(ws + BAR_OFF);
  unsigned short* hb   = (unsigned short*)(ws + HB_OFF);
  float*          hT   = (float*)(ws + HT_OFF);
  unsigned short* wx_t = (unsigned short*)(ws + WX_OFF);
  unsigned short* wh_t = (unsigned short*)(ws + WH_OFF);
  unsigned short* xgp  = (unsigned short*)(ws + XG_OFF);
  float*          part = (float*)(ws + PART_OFF);

  hipMemsetAsync(ws, 0, HB_OFF + 131072, stream);  // zero barrier + h buffer 0
  k_transpose<<<dim3(40, 128), 256, 0, stream>>>(kern, wx_t, wh_t);
  k_xgates<<<dim3(128, 64), 256, 0, stream>>>(x, wx_t, bias, xgp);
  k_lstm<<<dim3(256), 256, 0, stream>>>(wh_t, xgp, hb, hT, bar);
  k_proj<<<dim3(125, 4), 256, 0, stream>>>(w_out, hT, part);
  k_reduce<<<dim3(2000), 256, 0, stream>>>(part, b_out, out);
}

// Round 3
// 1579.000 us; speedup vs baseline: 2.2515x; 1.1980x over previous
//
#include <hip/hip_runtime.h>
#include <hip/hip_bf16.h>
#include <stdint.h>

#define B_ 64
#define T_ 128
#define E_ 256
#define H_ 1024
#define G_ 4096   // 4*H
#define V_ 32000
#define HS_ 65536 // elements per h buffer (64 rows x 1024 cols, bf16)

typedef __attribute__((ext_vector_type(8))) short short8;
typedef __attribute__((ext_vector_type(4))) float floatx4;

static __device__ __forceinline__ unsigned short f2bf(float f){
  union { float f; unsigned u; } v; v.f = f;
  unsigned r = v.u + 0x7FFFu + ((v.u >> 16) & 1u);  // RNE
  return (unsigned short)(r >> 16);
}
static __device__ __forceinline__ float bf2f(unsigned short s){
  union { unsigned u; float f; } v; v.u = ((unsigned)s) << 16;
  return v.f;
}
static __device__ __forceinline__ float sigmoidf_(float x){
  return 1.0f / (1.0f + __expf(-x));
}

// ---------------- transpose + bf16-convert the fused LSTM kernel ----------------
__global__ __launch_bounds__(256) void k_transpose(const float* __restrict__ kern,
    unsigned short* __restrict__ wx_t, unsigned short* __restrict__ wh_t){
  __shared__ float tile[32][36];
  const int k0 = blockIdx.x * 32, g0 = blockIdx.y * 32;
  const int r  = threadIdx.x >> 3;
  const int c4 = (threadIdx.x & 7) << 2;
  const float4 v = *reinterpret_cast<const float4*>(kern + (size_t)(k0 + r) * G_ + g0 + c4);
  tile[r][c4 + 0] = v.x; tile[r][c4 + 1] = v.y;
  tile[r][c4 + 2] = v.z; tile[r][c4 + 3] = v.w;
  __syncthreads();
  const unsigned short o0 = f2bf(tile[c4 + 0][r]);
  const unsigned short o1 = f2bf(tile[c4 + 1][r]);
  const unsigned short o2 = f2bf(tile[c4 + 2][r]);
  const unsigned short o3 = f2bf(tile[c4 + 3][r]);
  const ushort4 pk = make_ushort4(o0, o1, o2, o3);
  if (k0 < E_)
    *reinterpret_cast<ushort4*>(wx_t + (size_t)(g0 + r) * E_ + (k0 + c4)) = pk;
  else
    *reinterpret_cast<ushort4*>(wh_t + (size_t)(g0 + r) * H_ + (k0 - E_ + c4)) = pk;
}

// ---------------- xgates, PERMUTED for the LSTM ----------------
// xgp element ((t*256 + wg)*256 + lstm_tid)*4 + reg  (bf16),
// lstm_tid = w*64 + quad*16 + gate*4 + c for gate-col g = gate*1024 + wg*4 + c.
// Each block: 64 M-rows x 256 N-cols (16 n-tiles/wave) -> x re-read 16x not 64x.
__global__ __launch_bounds__(256) void k_xgates(const float* __restrict__ x,
    const unsigned short* __restrict__ wx_t, const float* __restrict__ bias,
    unsigned short* __restrict__ xgp){
  const int w = threadIdx.x >> 6, l = threadIdx.x & 63;
  const int quad = l >> 4, n = l & 15;
  const int Mbase = blockIdx.x * 64 + w * 16;
  const int Nbase = blockIdx.y * 256;
  const int r = Mbase + n;              // row = t*64 + b
  const int b = r & 63, t = r >> 6;
  const float* arow = x + ((size_t)b * T_ + t) * E_;
  floatx4 acc[16];
  #pragma unroll
  for (int i = 0; i < 16; ++i) acc[i] = (floatx4){0.f,0.f,0.f,0.f};
  #pragma unroll
  for (int kt = 0; kt < 8; ++kt){
    const int k0 = kt * 32 + quad * 8;
    const float4 f0 = *reinterpret_cast<const float4*>(arow + k0);
    const float4 f1 = *reinterpret_cast<const float4*>(arow + k0 + 4);
    short8 af;
    af[0] = (short)f2bf(f0.x); af[1] = (short)f2bf(f0.y);
    af[2] = (short)f2bf(f0.z); af[3] = (short)f2bf(f0.w);
    af[4] = (short)f2bf(f1.x); af[5] = (short)f2bf(f1.y);
    af[6] = (short)f2bf(f1.z); af[7] = (short)f2bf(f1.w);
    const unsigned short* bp = wx_t + (size_t)(Nbase + n) * E_ + k0;
    #pragma unroll
    for (int nt = 0; nt < 16; ++nt){
      const short8 bf = *reinterpret_cast<const short8*>(bp + (size_t)nt * 16 * E_);
      acc[nt] = __builtin_amdgcn_mfma_f32_16x16x32_bf16(af, bf, acc[nt], 0, 0, 0);
    }
  }
  // permuted 8B stores.  g = Nbase + nt*16 + nn  (nn = col within tile)
  const int t_out = blockIdx.x;
  const int gate = blockIdx.y >> 2;                   // g>>10
  const int np = gate * 4 + (n & 3);                  // gate*4 + c
  #pragma unroll
  for (int nt = 0; nt < 16; ++nt){
    const int g = Nbase + nt * 16 + n;
    const float bi = bias[g];
    const int wgd = (blockIdx.y & 3) * 64 + nt * 4 + (n >> 2);   // (g&1023)>>2
    ushort4 pk;
    pk.x = f2bf(acc[nt][0] + bi);
    pk.y = f2bf(acc[nt][1] + bi);
    pk.z = f2bf(acc[nt][2] + bi);
    pk.w = f2bf(acc[nt][3] + bi);
    *reinterpret_cast<ushort4*>(xgp +
        (((size_t)t_out * 256 + wgd) * 256 + w * 64 + quad * 16 + np) * 4) = pk;
  }
}

// ---------------- persistent LSTM: 256 WGs, 0 LDS, register-resident Wh slice ----------------
__global__ __launch_bounds__(256, 1) void k_lstm(const unsigned short* __restrict__ wh_t,
    const unsigned short* __restrict__ xgp, unsigned short* __restrict__ hb,
    float* __restrict__ hT, unsigned int* __restrict__ bar){
  const int tid = threadIdx.x;
  const int wg = blockIdx.x;                // owns h-cols [wg*4, wg*4+4)
  const int hbase = wg * 4;
  const int w = tid >> 6, l = tid & 63, quad = l >> 4, n = l & 15;
  const int g_lane = (n >> 2) * H_ + hbase + (n & 3);
  const int rowb = w * 16 + quad * 4;
  const bool low8  = (n & 8) == 0;          // lanes holding (i,j) pairs
  const bool first = (n & 4) == 0;          // first gate of the pair

  // Preload B-fragments (this WG's Wh slice): 32 x 16B per lane, then PIN them —
  // the empty asm makes the values opaque so LLVM cannot rematerialize the
  // loads inside the t-loop (round-2 failure mode: VGPR_Count=88, reloaded every step).
  short8 bfr[32];
  {
    const unsigned short* bp = wh_t + (size_t)g_lane * H_ + quad * 8;
    #pragma unroll
    for (int kt = 0; kt < 32; ++kt)
      bfr[kt] = *reinterpret_cast<const short8*>(bp + kt * 32);
  }
  #pragma unroll
  for (int kt = 0; kt < 32; ++kt)
    __asm__ volatile("" : "+v"(bfr[kt]));

  float creg[4] = {0.f, 0.f, 0.f, 0.f};

  for (int t = 0; t < T_; ++t){
    // A-fragments: one flat burst of 32 x 16B loads of h_t (fresh addresses
    // every step -> no cache can be stale; all 32 issue before first use)
    const unsigned short* asrc = hb + (size_t)t * HS_ + (size_t)(w * 16 + n) * H_ + quad * 8;
    short8 afr[32];
    #pragma unroll
    for (int kt = 0; kt < 32; ++kt)
      afr[kt] = *reinterpret_cast<const short8*>(asrc + kt * 32);
    const ushort4 xgv = *reinterpret_cast<const ushort4*>(
        xgp + (((size_t)t * 256 + wg) * 256 + tid) * 4);

    floatx4 a0 = {0.f,0.f,0.f,0.f}, a1 = {0.f,0.f,0.f,0.f};
    floatx4 a2 = {0.f,0.f,0.f,0.f}, a3 = {0.f,0.f,0.f,0.f};
    #pragma unroll
    for (int kt = 0; kt < 32; kt += 4){
      a0 = __builtin_amdgcn_mfma_f32_16x16x32_bf16(afr[kt + 0], bfr[kt + 0], a0, 0, 0, 0);
      a1 = __builtin_amdgcn_mfma_f32_16x16x32_bf16(afr[kt + 1], bfr[kt + 1], a1, 0, 0, 0);
      a2 = __builtin_amdgcn_mfma_f32_16x16x32_bf16(afr[kt + 2], bfr[kt + 2], a2, 0, 0, 0);
      a3 = __builtin_amdgcn_mfma_f32_16x16x32_bf16(afr[kt + 3], bfr[kt + 3], a3, 0, 0, 0);
    }
    floatx4 acc = (a0 + a1) + (a2 + a3);
    acc[0] += bf2f(xgv.x); acc[1] += bf2f(xgv.y);
    acc[2] += bf2f(xgv.z); acc[3] += bf2f(xgv.w);

    // pointwise: lane col n -> gate n>>2, h-offset n&3.  Pair up via shuffles.
    float r1o[4], q1[4], q2[4];
    #pragma unroll
    for (int reg = 0; reg < 4; ++reg){
      const float a_ = acc[reg];
      const float p_ = __shfl_xor(a_, 4);   // swap i<->j and f<->o
      const float x1 = first ? a_ : p_;     // i (low) / f (high)
      const float x2 = first ? p_ : a_;     // j (low) / o (high)
      const float s1 = sigmoidf_(low8 ? x1 : (x1 + 1.0f));   // sig(i) or sig(f+1)
      const float r1 = low8 ? s1 * tanhf(x2) : s1;           // sig(i)*tanh(j) or sig(f+1)
      const float r2 = low8 ? 0.0f : sigmoidf_(x2);          // sig(o)
      r1o[reg] = r1;
      q1[reg] = __shfl_xor(r1, 8);          // low lanes receive sig(f+1)
      q2[reg] = __shfl_xor(r2, 8);          // low lanes receive sig(o)
    }
    if (n < 4){
      unsigned short* hout = hb + (size_t)(t + 1) * HS_;
      #pragma unroll
      for (int reg = 0; reg < 4; ++reg){
        const float cn = creg[reg] * q1[reg] + r1o[reg];
        creg[reg] = cn;
        const float hv = tanhf(cn) * q2[reg];
        // agent-scope relaxed store -> write-through, visible at L3 once vmcnt drains
        __hip_atomic_store(&hout[(size_t)(rowb + reg) * H_ + hbase + n], f2bf(hv),
                           __ATOMIC_RELAXED, __HIP_MEMORY_SCOPE_AGENT);
        if (t == T_ - 1) hT[(size_t)(hbase + n) * B_ + rowb + reg] = hv;
      }
    }
    // Flat grid barrier: fire-and-forget add to 1-of-4 counters, poll the sum.
    // Counters are monotonic (one add per WG per step); sum == 256*(t+1) iff
    // every WG finished step t and its h stores were ACKed (vmcnt drained at
    // __syncthreads before the add was issued).
    if (t < T_ - 1){
      __syncthreads();
      if (tid == 0){
        const unsigned tgt = (unsigned)(t + 1) * 256u;
        __asm__ volatile("" ::: "memory");
        __hip_atomic_fetch_add(&bar[wg & 3], 1u, __ATOMIC_RELAXED, __HIP_MEMORY_SCOPE_AGENT);
        unsigned s;
        do {
          s = __hip_atomic_load(&bar[0], __ATOMIC_RELAXED, __HIP_MEMORY_SCOPE_AGENT)
            + __hip_atomic_load(&bar[1], __ATOMIC_RELAXED, __HIP_MEMORY_SCOPE_AGENT)
            + __hip_atomic_load(&bar[2], __ATOMIC_RELAXED, __HIP_MEMORY_SCOPE_AGENT)
            + __hip_atomic_load(&bar[3], __ATOMIC_RELAXED, __HIP_MEMORY_SCOPE_AGENT);
        } while (s < tgt);
        __asm__ volatile("" ::: "memory");
      }
      __syncthreads();
    }
  }
}

// ---------------- final projection: out = h127 @ w_out + b_out ----------------
__global__ __launch_bounds__(256) void k_proj(const float* __restrict__ w_out,
    const float* __restrict__ hT, float* __restrict__ part){
  __shared__ float wsh[32 * 260];
  __shared__ float hsh[32 * 68];
  const int tid = threadIdx.x;
  const int vb = blockIdx.x, ky = blockIdx.y;
  const int vq = tid & 63, bg = tid >> 6;
  const int vbase = vb * 256;
  floatx4 acc[16];
  #pragma unroll
  for (int i = 0; i < 16; ++i) acc[i] = (floatx4){0.f, 0.f, 0.f, 0.f};
  for (int c = 0; c < 8; ++c){
    const int k0 = ky * 256 + c * 32;
    __syncthreads();
    #pragma unroll
    for (int i = 0; i < 8; ++i){
      const int flat = tid + i * 256;
      const int row = flat >> 6, c4 = (flat & 63) << 2;
      *reinterpret_cast<float4*>(&wsh[row * 260 + c4]) =
        *reinterpret_cast<const float4*>(w_out + (size_t)(k0 + row) * V_ + vbase + c4);
    }
    #pragma unroll
    for (int i = 0; i < 2; ++i){
      const int flat = tid + i * 256;
      const int row = flat >> 4, c4 = (flat & 15) << 2;
      *reinterpret_cast<float4*>(&hsh[row * 68 + c4]) =
        *reinterpret_cast<const float4*>(hT + (k0 + row) * B_ + c4);
    }
    __syncthreads();
    #pragma unroll 4
    for (int k = 0; k < 32; ++k){
      const floatx4 wv = *reinterpret_cast<const floatx4*>(&wsh[k * 260 + vq * 4]);
      #pragma unroll
      for (int j = 0; j < 4; ++j){
        const floatx4 hv = *reinterpret_cast<const floatx4*>(&hsh[k * 68 + bg * 16 + j * 4]);
        acc[j * 4 + 0] += hv[0] * wv;
        acc[j * 4 + 1] += hv[1] * wv;
        acc[j * 4 + 2] += hv[2] * wv;
        acc[j * 4 + 3] += hv[3] * wv;
      }
    }
  }
  float* pbase = part + ((size_t)ky * B_ + bg * 16) * V_ + vbase + vq * 4;
  #pragma unroll
  for (int i = 0; i < 16; ++i){
    *reinterpret_cast<floatx4*>(pbase + (size_t)i * V_) = acc[i];
  }
}

__global__ __launch_bounds__(256) void k_reduce(const float* __restrict__ part,
    const float* __restrict__ b_out, float* __restrict__ out){
  const int f4 = blockIdx.x * 256 + threadIdx.x;          // 0..511999 float4s
  const floatx4* P = reinterpret_cast<const floatx4*>(part);
  floatx4 s = P[f4] + P[f4 + 512000] + P[f4 + 1024000] + P[f4 + 1536000];
  const int v = (f4 * 4) % V_;
  s += *reinterpret_cast<const floatx4*>(b_out + v);
  reinterpret_cast<floatx4*>(out)[f4] = s;
}

extern "C" void kernel_launch(void* const* d_in, const int* in_sizes, int n_in,
                              void* d_out, int out_size, void* d_ws, size_t ws_size,
                              hipStream_t stream){
  (void)in_sizes; (void)n_in; (void)out_size; (void)ws_size;
  const float* x     = (const float*)d_in[0];
  const float* kern  = (const float*)d_in[1];
  const float* bias  = (const float*)d_in[2];
  const float* w_out = (const float*)d_in[3];
  const float* b_out = (const float*)d_in[4];
  float* out = (float*)d_out;
  char* ws = (char*)d_ws;

  const size_t BAR_OFF = 0;                              // 4 KB barrier state
  const size_t HB_OFF  = 4096;                           // 129 h buffers, bf16 [64][1024]
  const size_t HT_OFF  = HB_OFF + (size_t)129 * 131072;  // h127 transposed fp32 [1024][64]
  const size_t WX_OFF  = HT_OFF + 262144;                // Wx^T bf16 [4096][256]
  const size_t WH_OFF  = WX_OFF + 2097152;               // Wh^T bf16 [4096][1024]
  const size_t XG_OFF  = WH_OFF + 8388608;               // xgates bf16 permuted (67 MB)
  const size_t PART_OFF = XG_OFF;                        // proj partials overlap xg

  unsigned int*   bar  = (unsigned int*)(ws + BAR_OFF);
  unsigned short* hb   = (unsigned short*)(ws + HB_OFF);
  float*          hT   = (float*)(ws + HT_OFF);
  unsigned short* wx_t = (unsigned short*)(ws + WX_OFF);
  unsigned short* wh_t = (unsigned short*)(ws + WH_OFF);
  unsigned short* xgp  = (unsigned short*)(ws + XG_OFF);
  float*          part = (float*)(ws + PART_OFF);

  hipMemsetAsync(ws, 0, HB_OFF + 131072, stream);  // zero barrier + h buffer 0
  k_transpose<<<dim3(40, 128), 256, 0, stream>>>(kern, wx_t, wh_t);
  k_xgates<<<dim3(128, 16), 256, 0, stream>>>(x, wx_t, bias, xgp);
  k_lstm<<<dim3(256), 256, 0, stream>>>(wh_t, xgp, hb, hT, bar);
  k_proj<<<dim3(125, 4), 256, 0, stream>>>(w_out, hT, part);
  k_reduce<<<dim3(2000), 256, 0, stream>>>(part, b_out, out);
}

// Round 4
// 1546.990 us; speedup vs baseline: 2.2981x; 1.0207x over previous
//
#include <hip/hip_runtime.h>
#include <hip/hip_bf16.h>
#include <stdint.h>

#define B_ 64
#define T_ 128
#define E_ 256
#define H_ 1024
#define G_ 4096   // 4*H
#define V_ 32000
#define HS_ 65536 // elements per h buffer (64 rows x 1024 cols, bf16)

typedef __attribute__((ext_vector_type(8))) short short8;
typedef __attribute__((ext_vector_type(4))) float floatx4;

static __device__ __forceinline__ unsigned short f2bf(float f){
  union { float f; unsigned u; } v; v.f = f;
  unsigned r = v.u + 0x7FFFu + ((v.u >> 16) & 1u);  // RNE
  return (unsigned short)(r >> 16);
}
static __device__ __forceinline__ float bf2f(unsigned short s){
  union { unsigned u; float f; } v; v.u = ((unsigned)s) << 16;
  return v.f;
}
static __device__ __forceinline__ float sigmoidf_(float x){
  return 1.0f / (1.0f + __expf(-x));
}
static __device__ __forceinline__ float tanhf_(float x){
  const float a = fabsf(x);
  const float t = 1.0f - 2.0f / (__expf(2.0f * a) + 1.0f);
  return __builtin_copysignf(t, x);
}

// ---------------- transpose + bf16-convert the fused LSTM kernel ----------------
__global__ __launch_bounds__(256) void k_transpose(const float* __restrict__ kern,
    unsigned short* __restrict__ wx_t, unsigned short* __restrict__ wh_t){
  __shared__ float tile[32][36];
  const int k0 = blockIdx.x * 32, g0 = blockIdx.y * 32;
  const int r  = threadIdx.x >> 3;
  const int c4 = (threadIdx.x & 7) << 2;
  const float4 v = *reinterpret_cast<const float4*>(kern + (size_t)(k0 + r) * G_ + g0 + c4);
  tile[r][c4 + 0] = v.x; tile[r][c4 + 1] = v.y;
  tile[r][c4 + 2] = v.z; tile[r][c4 + 3] = v.w;
  __syncthreads();
  const unsigned short o0 = f2bf(tile[c4 + 0][r]);
  const unsigned short o1 = f2bf(tile[c4 + 1][r]);
  const unsigned short o2 = f2bf(tile[c4 + 2][r]);
  const unsigned short o3 = f2bf(tile[c4 + 3][r]);
  const ushort4 pk = make_ushort4(o0, o1, o2, o3);
  if (k0 < E_)
    *reinterpret_cast<ushort4*>(wx_t + (size_t)(g0 + r) * E_ + (k0 + c4)) = pk;
  else
    *reinterpret_cast<ushort4*>(wh_t + (size_t)(g0 + r) * H_ + (k0 - E_ + c4)) = pk;
}

// ---------------- xgates, PERMUTED for the LSTM ----------------
// xgp element ((t*256 + wg)*256 + lstm_tid)*4 + reg  (bf16),
// lstm_tid = w*64 + quad*16 + gate*4 + c for gate-col g = gate*1024 + wg*4 + c.
__global__ __launch_bounds__(256) void k_xgates(const float* __restrict__ x,
    const unsigned short* __restrict__ wx_t, const float* __restrict__ bias,
    unsigned short* __restrict__ xgp){
  const int w = threadIdx.x >> 6, l = threadIdx.x & 63;
  const int quad = l >> 4, n = l & 15;
  const int Mbase = blockIdx.x * 64 + w * 16;
  const int Nbase = blockIdx.y * 256;
  const int r = Mbase + n;              // row = t*64 + b
  const int b = r & 63, t = r >> 6;
  const float* arow = x + ((size_t)b * T_ + t) * E_;
  floatx4 acc[16];
  #pragma unroll
  for (int i = 0; i < 16; ++i) acc[i] = (floatx4){0.f,0.f,0.f,0.f};
  #pragma unroll
  for (int kt = 0; kt < 8; ++kt){
    const int k0 = kt * 32 + quad * 8;
    const float4 f0 = *reinterpret_cast<const float4*>(arow + k0);
    const float4 f1 = *reinterpret_cast<const float4*>(arow + k0 + 4);
    short8 af;
    af[0] = (short)f2bf(f0.x); af[1] = (short)f2bf(f0.y);
    af[2] = (short)f2bf(f0.z); af[3] = (short)f2bf(f0.w);
    af[4] = (short)f2bf(f1.x); af[5] = (short)f2bf(f1.y);
    af[6] = (short)f2bf(f1.z); af[7] = (short)f2bf(f1.w);
    const unsigned short* bp = wx_t + (size_t)(Nbase + n) * E_ + k0;
    #pragma unroll
    for (int nt = 0; nt < 16; ++nt){
      const short8 bf = *reinterpret_cast<const short8*>(bp + (size_t)nt * 16 * E_);
      acc[nt] = __builtin_amdgcn_mfma_f32_16x16x32_bf16(af, bf, acc[nt], 0, 0, 0);
    }
  }
  const int t_out = blockIdx.x;
  const int gate = blockIdx.y >> 2;                   // g>>10
  const int np = gate * 4 + (n & 3);                  // gate*4 + c
  #pragma unroll
  for (int nt = 0; nt < 16; ++nt){
    const int g = Nbase + nt * 16 + n;
    const float bi = bias[g];
    const int wgd = (blockIdx.y & 3) * 64 + nt * 4 + (n >> 2);   // (g&1023)>>2
    ushort4 pk;
    pk.x = f2bf(acc[nt][0] + bi);
    pk.y = f2bf(acc[nt][1] + bi);
    pk.z = f2bf(acc[nt][2] + bi);
    pk.w = f2bf(acc[nt][3] + bi);
    *reinterpret_cast<ushort4*>(xgp +
        (((size_t)t_out * 256 + wgd) * 256 + w * 64 + quad * 16 + np) * 4) = pk;
  }
}

// ---------------- persistent LSTM: 256 WGs, 0 LDS ----------------
// Wh slice pinned in AGPRs (second register file; MFMA reads B from AGPR on
// gfx950) so the RA cannot spill it across the t-loop (round-3 failure mode).
// h-fragment loads pinned in VGPRs after a flat 32-load burst -> single
// s_waitcnt vmcnt(0), one L3 round-trip per step.
__global__ __launch_bounds__(256, 1) void k_lstm(const unsigned short* __restrict__ wh_t,
    const unsigned short* __restrict__ xgp, unsigned short* __restrict__ hb,
    float* __restrict__ hT, unsigned int* __restrict__ bar){
  const int tid = threadIdx.x;
  const int wg = blockIdx.x;                // owns h-cols [wg*4, wg*4+4)
  const int hbase = wg * 4;
  const int w = tid >> 6, l = tid & 63, quad = l >> 4, n = l & 15;
  const int g_lane = (n >> 2) * H_ + hbase + (n & 3);
  const int rowb = w * 16 + quad * 4;
  const bool low8  = (n & 8) == 0;          // lanes holding (i,j) pairs
  const bool first = (n & 4) == 0;          // first gate of the pair

  short8 bfr[32];
  {
    const unsigned short* bp = wh_t + (size_t)g_lane * H_ + quad * 8;
    #pragma unroll
    for (int kt = 0; kt < 32; ++kt)
      bfr[kt] = *reinterpret_cast<const short8*>(bp + kt * 32);
  }
  #pragma unroll
  for (int kt = 0; kt < 32; ++kt)
    __asm__ volatile("" : "+a"(bfr[kt]));   // park Wh in the AGPR file

  float creg[4] = {0.f, 0.f, 0.f, 0.f};
  ushort4 xgv = *reinterpret_cast<const ushort4*>(xgp + ((size_t)wg * 256 + tid) * 4);

  for (int t = 0; t < T_; ++t){
    // A-fragments: flat burst of 32 x 16B loads of h_t, pinned -> all in flight
    const unsigned short* asrc = hb + (size_t)t * HS_ + (size_t)(w * 16 + n) * H_ + quad * 8;
    short8 afr[32];
    #pragma unroll
    for (int kt = 0; kt < 32; ++kt)
      afr[kt] = *reinterpret_cast<const short8*>(asrc + kt * 32);
    #pragma unroll
    for (int kt = 0; kt < 32; ++kt)
      __asm__ volatile("" : "+v"(afr[kt]));

    floatx4 a0 = {0.f,0.f,0.f,0.f}, a1 = {0.f,0.f,0.f,0.f};
    floatx4 a2 = {0.f,0.f,0.f,0.f}, a3 = {0.f,0.f,0.f,0.f};
    #pragma unroll
    for (int kt = 0; kt < 32; kt += 4){
      a0 = __builtin_amdgcn_mfma_f32_16x16x32_bf16(afr[kt + 0], bfr[kt + 0], a0, 0, 0, 0);
      a1 = __builtin_amdgcn_mfma_f32_16x16x32_bf16(afr[kt + 1], bfr[kt + 1], a1, 0, 0, 0);
      a2 = __builtin_amdgcn_mfma_f32_16x16x32_bf16(afr[kt + 2], bfr[kt + 2], a2, 0, 0, 0);
      a3 = __builtin_amdgcn_mfma_f32_16x16x32_bf16(afr[kt + 3], bfr[kt + 3], a3, 0, 0, 0);
    }
    floatx4 acc = (a0 + a1) + (a2 + a3);
    acc[0] += bf2f(xgv.x); acc[1] += bf2f(xgv.y);
    acc[2] += bf2f(xgv.z); acc[3] += bf2f(xgv.w);

    // pointwise: lane col n -> gate n>>2, h-offset n&3.  Pair up via shuffles.
    float r1o[4], q1[4], q2[4];
    #pragma unroll
    for (int reg = 0; reg < 4; ++reg){
      const float a_ = acc[reg];
      const float p_ = __shfl_xor(a_, 4);   // swap i<->j and f<->o
      const float x1 = first ? a_ : p_;     // i (low) / f (high)
      const float x2 = first ? p_ : a_;     // j (low) / o (high)
      const float s1 = sigmoidf_(low8 ? x1 : (x1 + 1.0f));   // sig(i) or sig(f+1)
      const float r1 = low8 ? s1 * tanhf_(x2) : s1;          // sig(i)*tanh(j) or sig(f+1)
      const float r2 = low8 ? 0.0f : sigmoidf_(x2);          // sig(o)
      r1o[reg] = r1;
      q1[reg] = __shfl_xor(r1, 8);          // low lanes receive sig(f+1)
      q2[reg] = __shfl_xor(r2, 8);          // low lanes receive sig(o)
    }
    if (n < 4){
      unsigned short* hout = hb + (size_t)(t + 1) * HS_;
      #pragma unroll
      for (int reg = 0; reg < 4; ++reg){
        const float cn = creg[reg] * q1[reg] + r1o[reg];
        creg[reg] = cn;
        const float hv = tanhf_(cn) * q2[reg];
        __hip_atomic_store(&hout[(size_t)(rowb + reg) * H_ + hbase + n], f2bf(hv),
                           __ATOMIC_RELAXED, __HIP_MEMORY_SCOPE_AGENT);
        if (t == T_ - 1) hT[(size_t)(hbase + n) * B_ + rowb + reg] = hv;
      }
    }
    // Flat grid barrier: fire-and-forget add, poll the 4-counter sum.
    if (t < T_ - 1){
      // prefetch next step's x-gates so the load rides under the barrier
      const ushort4 xgv_n = *reinterpret_cast<const ushort4*>(
          xgp + (((size_t)(t + 1) * 256 + wg) * 256 + tid) * 4);
      __syncthreads();                      // drains h stores (vmcnt 0)
      if (tid == 0){
        const unsigned tgt = (unsigned)(t + 1) * 256u;
        __asm__ volatile("" ::: "memory");
        __hip_atomic_fetch_add(&bar[wg & 3], 1u, __ATOMIC_RELAXED, __HIP_MEMORY_SCOPE_AGENT);
        unsigned s;
        do {
          s = __hip_atomic_load(&bar[0], __ATOMIC_RELAXED, __HIP_MEMORY_SCOPE_AGENT)
            + __hip_atomic_load(&bar[1], __ATOMIC_RELAXED, __HIP_MEMORY_SCOPE_AGENT)
            + __hip_atomic_load(&bar[2], __ATOMIC_RELAXED, __HIP_MEMORY_SCOPE_AGENT)
            + __hip_atomic_load(&bar[3], __ATOMIC_RELAXED, __HIP_MEMORY_SCOPE_AGENT);
        } while (s < tgt);
        __asm__ volatile("" ::: "memory");
      }
      __syncthreads();
      xgv = xgv_n;
    }
  }
}

// ---------------- projection: out = h127 @ w_out + b_out, single pass ----------------
// grid 500, block 256: each block 64 v-cols x 64 b-rows, full K=1024, bias fused.
__global__ __launch_bounds__(256) void k_proj(const float* __restrict__ w_out,
    const float* __restrict__ hT, const float* __restrict__ b_out,
    float* __restrict__ out){
  __shared__ float wsh[32 * 68];
  __shared__ float hsh[32 * 68];
  const int tid = threadIdx.x;
  const int vbase = blockIdx.x * 64;
  const int vq = tid & 15, bg = tid >> 4;
  floatx4 acc[4] = {{0,0,0,0},{0,0,0,0},{0,0,0,0},{0,0,0,0}};
  for (int c = 0; c < 32; ++c){
    const int k0 = c * 32;
    __syncthreads();
    #pragma unroll
    for (int i = 0; i < 2; ++i){
      const int flat = tid + i * 256;
      const int row = flat >> 4, c4 = (flat & 15) << 2;
      *reinterpret_cast<float4*>(&wsh[row * 68 + c4]) =
        *reinterpret_cast<const float4*>(w_out + (size_t)(k0 + row) * V_ + vbase + c4);
      *reinterpret_cast<float4*>(&hsh[row * 68 + c4]) =
        *reinterpret_cast<const float4*>(hT + (size_t)(k0 + row) * B_ + c4);
    }
    __syncthreads();
    #pragma unroll 8
    for (int k = 0; k < 32; ++k){
      const floatx4 wv = *reinterpret_cast<const floatx4*>(&wsh[k * 68 + vq * 4]);
      #pragma unroll
      for (int j = 0; j < 4; ++j){
        acc[j] += hsh[k * 68 + bg * 4 + j] * wv;
      }
    }
  }
  const floatx4 bv = *reinterpret_cast<const floatx4*>(b_out + vbase + vq * 4);
  #pragma unroll
  for (int j = 0; j < 4; ++j){
    *reinterpret_cast<floatx4*>(out + (size_t)(bg * 4 + j) * V_ + vbase + vq * 4) = acc[j] + bv;
  }
}

extern "C" void kernel_launch(void* const* d_in, const int* in_sizes, int n_in,
                              void* d_out, int out_size, void* d_ws, size_t ws_size,
                              hipStream_t stream){
  (void)in_sizes; (void)n_in; (void)out_size; (void)ws_size;
  const float* x     = (const float*)d_in[0];
  const float* kern  = (const float*)d_in[1];
  const float* bias  = (const float*)d_in[2];
  const float* w_out = (const float*)d_in[3];
  const float* b_out = (const float*)d_in[4];
  float* out = (float*)d_out;
  char* ws = (char*)d_ws;

  const size_t BAR_OFF = 0;                              // 4 KB barrier state
  const size_t HB_OFF  = 4096;                           // 129 h buffers, bf16 [64][1024]
  const size_t HT_OFF  = HB_OFF + (size_t)129 * 131072;  // h127 transposed fp32 [1024][64]
  const size_t WX_OFF  = HT_OFF + 262144;                // Wx^T bf16 [4096][256]
  const size_t WH_OFF  = WX_OFF + 2097152;               // Wh^T bf16 [4096][1024]
  const size_t XG_OFF  = WH_OFF + 8388608;               // xgates bf16 permuted (67 MB)

  unsigned int*   bar  = (unsigned int*)(ws + BAR_OFF);
  unsigned short* hb   = (unsigned short*)(ws + HB_OFF);
  float*          hT   = (float*)(ws + HT_OFF);
  unsigned short* wx_t = (unsigned short*)(ws + WX_OFF);
  unsigned short* wh_t = (unsigned short*)(ws + WH_OFF);
  unsigned short* xgp  = (unsigned short*)(ws + XG_OFF);

  hipMemsetAsync(ws, 0, HB_OFF + 131072, stream);  // zero barrier + h buffer 0
  k_transpose<<<dim3(40, 128), 256, 0, stream>>>(kern, wx_t, wh_t);
  k_xgates<<<dim3(128, 16), 256, 0, stream>>>(x, wx_t, bias, xgp);
  k_lstm<<<dim3(256), 256, 0, stream>>>(wh_t, xgp, hb, hT, bar);
  k_proj<<<dim3(500), 256, 0, stream>>>(w_out, hT, b_out, out);
}